// Round 3
// baseline (211.708 us; speedup 1.0000x reference)
//
#include <hip/hip_runtime.h>

#define BLK 256
#define CH 30

__global__ __launch_bounds__(BLK) void yolo_loss_kernel(
    const float* __restrict__ pred, const float* __restrict__ targ,
    float* __restrict__ out, int ncells, float inv_n)
{
    __shared__ float sp[BLK * CH];
    __shared__ float st[BLK * CH];
    const int tid = threadIdx.x;
    const long long base_cell = (long long)blockIdx.x * BLK;
    const long long rem = (long long)ncells - base_cell;
    const int nc = rem >= BLK ? BLK : (int)rem;

    if (nc == BLK) {
        // full block: coalesced float4 staging (block base is 16B aligned:
        // 256*30*4 = 30720 bytes per block)
        const float4* gp = (const float4*)(pred + base_cell * CH);
        const float4* gt = (const float4*)(targ + base_cell * CH);
        float4* lp = (float4*)sp;
        float4* lt = (float4*)st;
        for (int j = tid; j < BLK * CH / 4; j += BLK) {
            lp[j] = gp[j];
            lt[j] = gt[j];
        }
    } else {
        for (int j = tid; j < nc * CH; j += BLK) {
            sp[j] = pred[base_cell * CH + j];
            st[j] = targ[base_cell * CH + j];
        }
    }
    __syncthreads();

    float loss = 0.0f;
    if (tid < nc) {
        const float* p = sp + tid * CH;
        const float* t = st + tid * CH;

        const float conf_t = t[4];

        // target box -> xyxy
        const float tw = t[2], th = t[3];
        const float tx = t[0] / 14.0f, ty = t[1] / 14.0f;
        const float tx1 = tx - 0.5f * tw, ty1 = ty - 0.5f * th;
        const float tx2 = tx + 0.5f * tw, ty2 = ty + 0.5f * th;
        const float ta = tw * th;

        float iou0, iou1;
        #pragma unroll
        for (int b = 0; b < 2; ++b) {
            const float* pb = p + b * 5;
            const float pw = pb[2], ph = pb[3];
            const float px = pb[0] / 14.0f, py = pb[1] / 14.0f;
            const float x1 = px - 0.5f * pw, y1 = py - 0.5f * ph;
            const float x2 = px + 0.5f * pw, y2 = py + 0.5f * ph;
            const float ltx = fmaxf(x1, tx1), lty = fmaxf(y1, ty1);
            const float rbx = fminf(x2, tx2), rby = fminf(y2, ty2);
            const float w = fmaxf(rbx - ltx, 0.0f);
            const float h = fmaxf(rby - lty, 0.0f);
            const float inter = w * h;
            const float a1 = pw * ph;
            const float v = inter / (a1 + ta - inter);
            if (b == 0) iou0 = v; else iou1 = v;
        }

        // argmax (first-max on ties -> strict >)
        const int resp = (iou1 > iou0) ? 1 : 0;
        const float max_iou = fmaxf(iou0, iou1);
        const float* br = p + resp * 5;
        const float* bn = p + (1 - resp) * 5;

        const float coo = (conf_t > 0.0f) ? 1.0f : 0.0f;
        const float noo = (conf_t == 0.0f) ? 1.0f : 0.0f;

        const float d0 = br[0] - t[0];
        const float d1 = br[1] - t[1];
        const float d2 = sqrtf(br[2]) - sqrtf(t[2]);
        const float d3 = sqrtf(br[3]) - sqrtf(t[3]);
        const float loc = d0 * d0 + d1 * d1 + d2 * d2 + d3 * d3;

        const float dc = br[4] - max_iou;
        const float contain = dc * dc;
        const float ncontain = bn[4] * bn[4];

        const float n4 = p[4] - t[4];
        const float n9 = p[9] - t[9];
        const float noobj = n4 * n4 + n9 * n9;

        float cls = 0.0f;
        #pragma unroll
        for (int c = 10; c < 30; ++c) {
            const float d = p[c] - t[c];
            cls += d * d;
        }

        loss = coo * (5.0f * loc + 2.0f * contain + ncontain + cls)
             + 0.5f * noo * noobj;
    }

    // wave reduce (64 lanes)
    float v = loss;
    #pragma unroll
    for (int off = 32; off > 0; off >>= 1) v += __shfl_down(v, off);

    __shared__ float wsum[BLK / 64];
    const int wid = tid >> 6;
    const int lane = tid & 63;
    if (lane == 0) wsum[wid] = v;
    __syncthreads();
    if (tid == 0) {
        float s = 0.0f;
        #pragma unroll
        for (int w = 0; w < BLK / 64; ++w) s += wsum[w];
        atomicAdd(out, s * inv_n);
    }
}

extern "C" void kernel_launch(void* const* d_in, const int* in_sizes, int n_in,
                              void* d_out, int out_size, void* d_ws, size_t ws_size,
                              hipStream_t stream) {
    const float* pred = (const float*)d_in[0];
    const float* targ = (const float*)d_in[1];
    float* out = (float*)d_out;

    const long long total = in_sizes[0];
    const int ncells = (int)(total / CH);          // 4096*14*14 = 802816
    const int N = ncells / 196;                    // 4096
    const float inv_n = 1.0f / (float)N;

    hipMemsetAsync(out, 0, sizeof(float) * out_size, stream);

    const int grid = (ncells + BLK - 1) / BLK;     // 3136
    hipLaunchKernelGGL(yolo_loss_kernel, dim3(grid), dim3(BLK), 0, stream,
                       pred, targ, out, ncells, inv_n);
}

// Round 4
// 210.116 us; speedup vs baseline: 1.0076x; 1.0076x over previous
//
#include <hip/hip_runtime.h>

#define BLK 128            // threads per block == cells per tile
#define CH 30
#define TILE_FLOATS (BLK * CH)          // 3840 floats = 15360 B per tensor
#define CHUNKS 15                       // 15 x 1024B chunks per tensor per tile

// async global->LDS, 16B per lane, wave-uniform LDS base (HW adds lane*16)
__device__ __forceinline__ void gld_lds16(const float* g, float* l) {
    __builtin_amdgcn_global_load_lds(
        (const __attribute__((address_space(1))) void*)(const void*)g,
        (__attribute__((address_space(3))) void*)(void*)l,
        16, 0, 0);
}

__device__ __forceinline__ float cell_loss(const float* __restrict__ p,
                                           const float* __restrict__ t) {
    const float conf_t = t[4];

    // target box -> xyxy (exact /14.0f to match numpy argmax decisions)
    const float tw = t[2], th = t[3];
    const float tx = t[0] / 14.0f, ty = t[1] / 14.0f;
    const float tx1 = tx - 0.5f * tw, ty1 = ty - 0.5f * th;
    const float tx2 = tx + 0.5f * tw, ty2 = ty + 0.5f * th;
    const float ta = tw * th;

    float iou0, iou1;
    #pragma unroll
    for (int b = 0; b < 2; ++b) {
        const float* pb = p + b * 5;
        const float pw = pb[2], ph = pb[3];
        const float px = pb[0] / 14.0f, py = pb[1] / 14.0f;
        const float x1 = px - 0.5f * pw, y1 = py - 0.5f * ph;
        const float x2 = px + 0.5f * pw, y2 = py + 0.5f * ph;
        const float ltx = fmaxf(x1, tx1), lty = fmaxf(y1, ty1);
        const float rbx = fminf(x2, tx2), rby = fminf(y2, ty2);
        const float w = fmaxf(rbx - ltx, 0.0f);
        const float h = fmaxf(rby - lty, 0.0f);
        const float inter = w * h;
        const float a1 = pw * ph;
        const float v = inter / (a1 + ta - inter);
        if (b == 0) iou0 = v; else iou1 = v;
    }

    const int resp = (iou1 > iou0) ? 1 : 0;      // argmax, first-max ties
    const float max_iou = fmaxf(iou0, iou1);
    const float* br = p + resp * 5;
    const float* bn = p + (1 - resp) * 5;

    const float coo = (conf_t > 0.0f) ? 1.0f : 0.0f;
    const float noo = (conf_t == 0.0f) ? 1.0f : 0.0f;

    const float d0 = br[0] - t[0];
    const float d1 = br[1] - t[1];
    const float d2 = sqrtf(br[2]) - sqrtf(t[2]);
    const float d3 = sqrtf(br[3]) - sqrtf(t[3]);
    const float loc = d0 * d0 + d1 * d1 + d2 * d2 + d3 * d3;

    const float dc = br[4] - max_iou;
    const float contain = dc * dc;
    const float ncontain = bn[4] * bn[4];

    const float n4 = p[4] - t[4];
    const float n9 = p[9] - t[9];
    const float noobj = n4 * n4 + n9 * n9;

    float cls = 0.0f;
    #pragma unroll
    for (int c = 10; c < 30; ++c) {
        const float d = p[c] - t[c];
        cls += d * d;
    }

    return coo * (5.0f * loc + 2.0f * contain + ncontain + cls)
         + 0.5f * noo * noobj;
}

__global__ __launch_bounds__(BLK) void yolo_loss_kernel(
    const float* __restrict__ pred, const float* __restrict__ targ,
    float* __restrict__ out, int tpb, float inv_n)
{
    // [buf][tensor][tile data]; 2*2*15360 = 61440 B -> 2 blocks/CU
    __shared__ __align__(16) float lds[2][2][TILE_FLOATS];
    const int tid  = threadIdx.x;
    const int lane = tid & 63;
    const int wave = tid >> 6;           // wave 0 stages pred, wave 1 targ

    const long long t0 = (long long)blockIdx.x * tpb;
    const float* gsrc = (wave == 0) ? pred : targ;

    // ---- stage tile (t0 + i) into lds[buf] : 15 async 1KB chunks per wave
    auto STAGE = [&](int buf, long long t) {
        const float* g = gsrc + t * TILE_FLOATS + lane * 4;
        float* l = &lds[buf][wave][0];
        #pragma unroll
        for (int k = 0; k < CHUNKS; ++k)
            gld_lds16(g + k * 256, l + k * 256);
    };

    STAGE(0, t0);                         // prologue: 15 loads in flight

    float acc = 0.0f;
    for (int i = 0; i < tpb; ++i) {
        const int cur = i & 1;
        if (i + 1 < tpb) {
            STAGE(cur ^ 1, t0 + i + 1);   // issue next tile (15 more loads)
            asm volatile("s_waitcnt vmcnt(15)" ::: "memory");  // tile i done
        } else {
            asm volatile("s_waitcnt vmcnt(0)" ::: "memory");
        }
        __builtin_amdgcn_s_barrier();     // raw barrier: no vmcnt(0) drain

        acc += cell_loss(&lds[cur][0][tid * CH], &lds[cur][1][tid * CH]);

        asm volatile("" ::: "memory");    // keep ds_reads before the barrier
        __builtin_amdgcn_s_barrier();     // reads done before next overwrite
    }

    // wave shuffle-reduce; one atomic per wave (2/block)
    #pragma unroll
    for (int off = 32; off > 0; off >>= 1) acc += __shfl_down(acc, off);
    if (lane == 0) atomicAdd(out, acc * inv_n);
}

extern "C" void kernel_launch(void* const* d_in, const int* in_sizes, int n_in,
                              void* d_out, int out_size, void* d_ws, size_t ws_size,
                              hipStream_t stream) {
    const float* pred = (const float*)d_in[0];
    const float* targ = (const float*)d_in[1];
    float* out = (float*)d_out;

    const long long total = in_sizes[0];          // 4096*14*14*30
    const int ncells = (int)(total / CH);         // 802816 (divisible by 128)
    const int N = ncells / 196;                   // 4096
    const float inv_n = 1.0f / (float)N;

    const int ntiles = ncells / BLK;              // 6272
    int grid, tpb;
    if (ntiles % 448 == 0) { grid = 448; tpb = ntiles / 448; }  // 14 tiles each
    else                   { grid = ntiles; tpb = 1; }          // fallback

    hipMemsetAsync(out, 0, sizeof(float) * out_size, stream);
    hipLaunchKernelGGL(yolo_loss_kernel, dim3(grid), dim3(BLK), 0, stream,
                       pred, targ, out, tpb, inv_n);
}